// Round 3
// 282.922 us; speedup vs baseline: 1.0798x; 1.0798x over previous
//
#include <hip/hip_runtime.h>

// PillarQueryAndGroup: three dense-domain unique/rank ops via bitmap+popcount
// prefix sum, plus per-point feature assembly (gathers collapse to per-point
// math since f_center[inv[i]] is point i's own bin center).
//
// R1: split wave-per-point finalize into linear float2 features kernel +
// thread-per-point coords kernel; barrier-free shuffle scan1; blocked scan2.
// R2: pipeline slimming — 8 dispatches -> 5:
//   - scatter_bits fused into features kernel (atomics hide under the 220MB
//     streaming pass; drops a separate 4MB read pass + a launch)
//   - fill_neg1 deleted: coords_kernel writes -1 tails for slots [uniq, n)
//     (ranks are dense, so those are exactly the invalid rows); scan2 now
//     publishes the grand total at chunkPrefix[N_CHUNKS]
//   - wordPrefix u32 -> u16 (in-chunk prefix <= 16384): scan1 writes halve,
//     coords random-read footprint halves
//   - scan2 widened to 1024 threads: 43 -> 11 serial loads on critical path
// R3/R4: resubmits — R1 and R2 both died at container level (no pass/fail,
//     no counters). Source audited twice for OOB / deadlock / alignment /
//     graph-capture hazards; none found. Treating as infra flake.

namespace {
constexpr int   Hc  = 1440, Wc = 1440;
constexpr float Pf  = 0.075f, VZf = 0.25f, VTf = 0.05f;
constexpr int   GZi = 32, GTi = 10;
constexpr float ZCf = 4.0f, TZCf = 5.0f;

// Bitmap layout: three regions concatenated, each padded to 256-word chunks.
// Region A (flat2): 2*1440*1440 bits = 64,800 words -> pad 65,024 (254 chunks)
// Region B (flat3): *32 -> 2,073,600 words (8,100 chunks exactly)
// Region C (flatt): *10 ->   648,000 words -> pad 648,192 (2,532 chunks)
constexpr unsigned REGB_WORD  = 65024u;
constexpr unsigned REGC_WORD  = 2138624u;   // 65,024 + 2,073,600
constexpr unsigned TOT_WORDS  = 2786816u;   // REGC_WORD + 648,192
constexpr unsigned N_CHUNKS   = 10886u;     // TOT_WORDS / 256
constexpr unsigned REGB_CHUNK = 254u;
constexpr unsigned REGC_CHUNK = 8354u;
}

// Linear float2 kernel over the three n*70 feature arrays, with the bitmap
// scatter fused in (one lane per point, c2==34, does the 3 atomicOr's —
// their latency hides under this kernel's 220MB of streaming traffic).
// idx in [0, 35n): i = idx/35, c2 = idx%35. c2<32 -> pf copy; else tail math.
__global__ __launch_bounds__(256) void features_scatter_kernel(
    const float* xyzt, const float* pf, const int* cnt, int n,
    unsigned long long* bitmap, float* out) {
  unsigned idx = blockIdx.x * blockDim.x + threadIdx.x;
  unsigned tot = 35u * (unsigned)n;
  if (idx >= tot) return;
  unsigned i = idx / 35u;
  unsigned c2 = idx - i * 35u;
  size_t nn = (size_t)n;
  float2* f  = (float2*)(out + 4 * nn);      // features  (4n even)
  float2* zf = (float2*)(out + 79 * nn);     // z_features(79n even for n=200k)
  float2* tf = (float2*)(out + 154 * nn);    // t_features
  size_t r = (size_t)i * 35 + c2;
  float2 v, vt;
  if (c2 < 32u) {
    v = ((const float2*)pf)[(size_t)i * 32 + c2];
    vt = v;
  } else {
    const float* p = xyzt + (size_t)i * 5;
    float x = p[0], y = p[1], z = p[2], t = p[4];
    int ix = (int)(x / Pf), iy = (int)(y / Pf);   // IEEE div matches reference
    float cx = ((float)ix + 0.5f) * Pf, cy = ((float)iy + 0.5f) * Pf;
    if (c2 == 32u)      { v = make_float2(x, y);        vt = v; }
    else if (c2 == 33u) { v = make_float2(z, x - cx);   vt = make_float2(t, x - cx); }
    else {
      v = make_float2(y - cy, z - ZCf); vt = make_float2(y - cy, t - TZCf);
      // ---- fused bitmap scatter: exactly one lane per point ----
      int bb = (i >= (unsigned)cnt[0]) ? 1 : 0;
      int iz = (int)(z / VZf), it = (int)(t / VTf);
      unsigned f2 = (unsigned)((bb * Hc + iy) * Wc + ix);
      unsigned f3 = f2 * (unsigned)GZi + (unsigned)iz;
      unsigned ft = f2 * (unsigned)GTi + (unsigned)it;
      atomicOr(&bitmap[f2 >> 6], 1ull << (f2 & 63));
      atomicOr(&bitmap[REGB_WORD + (f3 >> 6)], 1ull << (f3 & 63));
      atomicOr(&bitmap[REGC_WORD + (ft >> 6)], 1ull << (ft & 63));
    }
  }
  f[r] = v; zf[r] = v; tf[r] = vt;           // z_features == features
}

// One wave per 256-word chunk, barrier-free: each lane popcounts 4 words,
// shuffle-scan across 64 lanes, ushort4 store of per-word exclusive prefixes.
// In-chunk prefix <= 256*64 = 16384, so u16 is lossless.
__global__ __launch_bounds__(256) void scan1_kernel(
    const unsigned long long* bitmap, unsigned short* wordPrefix, unsigned* chunkSums) {
  unsigned tid = threadIdx.x;
  unsigned lane = tid & 63u;
  unsigned chunk = blockIdx.x * 4u + (tid >> 6);
  if (chunk >= N_CHUNKS) return;
  unsigned wbase = chunk * 256u + lane * 4u;
  const ulonglong2* bp = (const ulonglong2*)(bitmap + wbase);
  ulonglong2 w01 = bp[0], w23 = bp[1];
  unsigned p0 = (unsigned)__popcll(w01.x), p1 = (unsigned)__popcll(w01.y);
  unsigned p2 = (unsigned)__popcll(w23.x), p3 = (unsigned)__popcll(w23.y);
  unsigned lsum = p0 + p1 + p2 + p3;
  unsigned x = lsum;
  #pragma unroll
  for (int d = 1; d < 64; d <<= 1) {
    unsigned o = __shfl_up(x, d, 64);
    if ((int)lane >= d) x += o;
  }
  unsigned excl = x - lsum;                  // exclusive across lanes
  ushort4 wp;
  wp.x = (unsigned short)excl;
  wp.y = (unsigned short)(excl + p0);
  wp.z = (unsigned short)(excl + p0 + p1);
  wp.w = (unsigned short)(excl + p0 + p1 + p2);
  *(ushort4*)(wordPrefix + wbase) = wp;      // 8B store, 8B-aligned
  if (lane == 63u) chunkSums[chunk] = x;     // chunk total
}

// Single-block exclusive scan over 10,886 chunk sums: 11 elements/thread
// serial, one 1024-wide LDS block scan, serial prefix write-back.
// Also publishes the grand total at chunkPrefix[N_CHUNKS].
__global__ __launch_bounds__(1024) void scan2_kernel(
    const unsigned* chunkSums, unsigned* chunkPrefix) {
  __shared__ unsigned s[1024];
  unsigned tid = threadIdx.x;
  const unsigned K = (N_CHUNKS + 1023u) / 1024u;   // 11
  unsigned base = tid * K;
  unsigned end = min(base + K, N_CHUNKS);
  unsigned sum = 0;
  for (unsigned j = base; j < end; ++j) sum += chunkSums[j];
  s[tid] = sum;
  __syncthreads();
  for (int o = 1; o < 1024; o <<= 1) {
    unsigned v = (tid >= (unsigned)o) ? s[tid - o] : 0u;
    __syncthreads();
    s[tid] += v;
    __syncthreads();
  }
  unsigned run = s[tid] - sum;               // exclusive across threads
  for (unsigned j = base; j < end; ++j) {
    unsigned v = chunkSums[j];
    chunkPrefix[j] = run;
    run += v;
  }
  if (tid == 1023u) chunkPrefix[N_CHUNKS] = s[1023];   // grand total
}

// Thread-per-point: 3 rank lookups, write inv (coalesced) + scatter coords.
// Tail fill fused in: ranks are dense [0, uniq), so slots [uniq, n) of each
// coords array are exactly the -1 rows — thread i fills slot i when i >= uniq.
__global__ __launch_bounds__(256) void coords_kernel(
    const float* xyzt, const int* cnt, int n,
    const unsigned long long* bitmap, const unsigned short* wordPrefix,
    const unsigned* chunkPrefix, float* out) {
  int i = blockIdx.x * blockDim.x + threadIdx.x;
  if (i >= n) return;
  int cnt0 = cnt[0];
  const float* p = xyzt + (size_t)i * 5;
  float x = p[0], y = p[1], z = p[2], t = p[4];
  int ix = (int)(x / Pf), iy = (int)(y / Pf);
  int iz = (int)(z / VZf), it = (int)(t / VTf);
  int bb = (i >= cnt0) ? 1 : 0;

  size_t nn = (size_t)n;
  const size_t o_coords  = 0,        o_inv2 = 3 * nn;
  const size_t o_coordsZ = 74 * nn,  o_inv3 = 78 * nn;
  const size_t o_coordsT = 149 * nn, o_invt = 153 * nn;

  // Region totals (uniform scalar loads, L2-hot).
  unsigned cumA = chunkPrefix[REGB_CHUNK];        // = uniqA
  unsigned cumB = chunkPrefix[REGC_CHUNK];        // = uniqA + uniqZ
  unsigned cumT = chunkPrefix[N_CHUNKS];          // grand total
  unsigned uniqA = cumA, uniqZ = cumB - cumA, uniqT = cumT - cumB;

  unsigned f2 = (unsigned)((bb * Hc + iy) * Wc + ix);
  unsigned f3 = f2 * (unsigned)GZi + (unsigned)iz;
  unsigned ft = f2 * (unsigned)GTi + (unsigned)it;
  auto rank = [&](unsigned wordOff, unsigned vv) -> unsigned {
    unsigned w = wordOff + (vv >> 6);
    unsigned bit = vv & 63u;
    return chunkPrefix[w >> 8] + (unsigned)wordPrefix[w] +
           (unsigned)__popcll(bitmap[w] & ((1ull << bit) - 1ull));
  };
  unsigned r2 = rank(0u, f2);                     // base A = 0
  unsigned r3 = rank(REGB_WORD, f3) - cumA;
  unsigned rt = rank(REGC_WORD, ft) - cumB;
  out[o_inv2 + i] = (float)r2;
  out[o_inv3 + i] = (float)r3;
  out[o_invt + i] = (float)rt;
  float* pc2 = out + o_coords + (size_t)r2 * 3;
  pc2[0] = (float)bb; pc2[1] = (float)iy; pc2[2] = (float)ix;
  float* pz = out + o_coordsZ + (size_t)r3 * 4;
  pz[0] = (float)bb; pz[1] = (float)iz; pz[2] = (float)iy; pz[3] = (float)ix;
  float* pt = out + o_coordsT + (size_t)rt * 4;
  pt[0] = (float)bb; pt[1] = (float)it; pt[2] = (float)iy; pt[3] = (float)ix;

  // -1 tails (disjoint from rank-scatter slots above).
  if ((unsigned)i >= uniqA) {
    float* q = out + o_coords + (size_t)i * 3;
    q[0] = -1.f; q[1] = -1.f; q[2] = -1.f;
  }
  if ((unsigned)i >= uniqZ) {
    float4* q = (float4*)(out + o_coordsZ) + i;   // 74n floats: 16B-aligned
    *q = make_float4(-1.f, -1.f, -1.f, -1.f);
  }
  if ((unsigned)i >= uniqT) {
    // 149n floats: odd multiple-of-4-bytes base -> keep scalar stores.
    float* qs = out + o_coordsT + (size_t)i * 4;
    qs[0] = -1.f; qs[1] = -1.f; qs[2] = -1.f; qs[3] = -1.f;
  }
}

extern "C" void kernel_launch(void* const* d_in, const int* in_sizes, int n_in,
                              void* d_out, int out_size, void* d_ws, size_t ws_size,
                              hipStream_t stream) {
  const float* xyzt = (const float*)d_in[0];
  const int*   cnt  = (const int*)d_in[1];
  const float* pf   = (const float*)d_in[2];
  float* out = (float*)d_out;
  int n = in_sizes[0] / 5;

  // Workspace: bitmap (22.3MB) | wordPrefix u16 (5.6MB) | chunkSums | chunkPrefix
  unsigned long long* bitmap = (unsigned long long*)d_ws;
  unsigned short* wordPrefix = (unsigned short*)((char*)d_ws + (size_t)TOT_WORDS * 8);
  unsigned* chunkSums   = (unsigned*)((char*)d_ws + (size_t)TOT_WORDS * 10);
  unsigned* chunkPrefix = chunkSums + ((N_CHUNKS + 7u) & ~7u);

  hipMemsetAsync(bitmap, 0, (size_t)TOT_WORDS * 8, stream);

  features_scatter_kernel<<<(35u * (unsigned)n + 255) / 256, 256, 0, stream>>>(
      xyzt, pf, cnt, n, bitmap, out);

  scan1_kernel<<<(N_CHUNKS + 3) / 4, 256, 0, stream>>>(bitmap, wordPrefix, chunkSums);
  scan2_kernel<<<1, 1024, 0, stream>>>(chunkSums, chunkPrefix);

  coords_kernel<<<(n + 255) / 256, 256, 0, stream>>>(xyzt, cnt, n,
                                                     bitmap, wordPrefix, chunkPrefix, out);
}